// Round 3
// baseline (350.702 us; speedup 1.0000x reference)
//
#include <hip/hip_runtime.h>
#include <stdint.h>

#define T_DIM 2048
#define B_DIM 16
#define H_DIM 1024
#define M_DIM (T_DIM * B_DIM)   // 32768 rows
#define BK 64
#define TCHUNK 32
#define CONV_BLOCKS 2048

typedef __attribute__((ext_vector_type(8))) short bf16x8;
typedef __attribute__((ext_vector_type(4))) float floatx4;

__device__ inline unsigned short f2bf(float f) {
  union { float f; unsigned int u; } c; c.f = f;
  unsigned int u = c.u;
  return (unsigned short)((u + 0x7FFFu + ((u >> 16) & 1u)) >> 16);  // RNE
}

__device__ inline float bf2f(unsigned short u) {
  union { float f; unsigned int u; } c; c.u = ((unsigned int)u) << 16;
  return c.f;
}

__device__ inline float fast_tanh(float x) {
  float e = __expf(2.0f * x);
  return 1.0f - 2.0f / (e + 1.0f);
}

// ---------------- fused prep: X fp32->bf16 (grid-stride) + W transpose ------
// blocks [0, CONV_BLOCKS): convert 128 MB x -> 64 MB bf16 Xb, 16 float4/thread
//   (R0's 32768 x 4KB one-shot blocks risked launch-rate limit; Guideline 11).
// blocks [CONV_BLOCKS, CONV_BLOCKS+1024): W[K][N] fp32 -> Wt[N][K] bf16.
__global__ void prep_kernel(const float* __restrict__ x,
                            unsigned short* __restrict__ xb,
                            const float* __restrict__ w,
                            unsigned short* __restrict__ wt) {
  __shared__ float tile[32][33];
  if (blockIdx.x < CONV_BLOCKS) {
    size_t i = ((size_t)blockIdx.x * 256 + threadIdx.x) * 4;
    const size_t stride = (size_t)CONV_BLOCKS * 256 * 4;   // elems per sweep
    #pragma unroll
    for (int it = 0; it < 16; ++it, i += stride) {
      float4 v = *(const float4*)(x + i);
      ushort4 o;
      o.x = f2bf(v.x); o.y = f2bf(v.y); o.z = f2bf(v.z); o.w = f2bf(v.w);
      *(ushort4*)(xb + i) = o;
    }
  } else {
    int bid = blockIdx.x - CONV_BLOCKS;
    int tx = threadIdx.x & 31, ty = threadIdx.x >> 5;   // (32, 8)
    int n0 = (bid & 31) * 32, k0 = (bid >> 5) * 32;
    for (int i = ty; i < 32; i += 8)
      tile[i][tx] = w[(size_t)(k0 + i) * H_DIM + n0 + tx];
    __syncthreads();
    for (int i = ty; i < 32; i += 8)
      wt[(size_t)(n0 + i) * H_DIM + k0 + tx] = f2bf(tile[tx][i]);
  }
}

// ---------------- scores = tanh(X@W)@proj ----------------
// PROVEN R0 structure (78.8-79.2 us measured): 128-row slab x 256-col split,
// 256 thr / 4 waves, 32 KiB LDS -> ~2.6 blocks/CU so inter-block overlap
// (m114) hides the per-K-step barrier drain. R1/R2's 256^2 1-block/CU
// rewrites lost that overlap (93/96 us) -> reverted.
// XCD swizzle: 4 N-splits of one 128-row A-slab land on the same XCD,
// dispatch-adjacent -> A fetched once per XCD.
__global__ __launch_bounds__(256, 4)
void score_gemm_kernel(const unsigned short* __restrict__ Xb,
                       const unsigned short* __restrict__ Wt,
                       const float* __restrict__ proj,
                       float* __restrict__ scores) {
  __shared__ __align__(16) unsigned short ldsA[128 * BK];
  __shared__ __align__(16) unsigned short ldsB[128 * BK];

  const int tid  = threadIdx.x;
  const int lane = tid & 63;
  const int wave = tid >> 6;
  const int wy = wave >> 1, wx = wave & 1;
  const int quad = lane >> 4, l16 = lane & 15;

  const int idx   = blockIdx.x;
  const int x7    = idx & 7;
  const int split = (idx >> 3) & 3;
  const int g     = idx >> 5;
  const int bm    = g * 8 + x7;        // 0..255
  const int m0    = bm * 128;
  const int nbase = split * 256;

  int ldsOff[4];
  int rowOff[4];
  #pragma unroll
  for (int i = 0; i < 4; ++i) {
    int cb = (i * 4 + wave) * 64;
    int s = cb + lane;
    int row = s >> 3, cs = s & 7;
    int cg = cs ^ (row & 7);
    ldsOff[i] = cb;
    rowOff[i] = row * H_DIM + cg * 8;
  }

  float sc[4][4];
  #pragma unroll
  for (int a = 0; a < 4; ++a)
    #pragma unroll
    for (int b = 0; b < 4; ++b) sc[a][b] = 0.0f;

  for (int n0 = nbase; n0 < nbase + 256; n0 += 128) {
    floatx4 acc[4][4];
    #pragma unroll
    for (int a = 0; a < 4; ++a)
      #pragma unroll
      for (int b = 0; b < 4; ++b) acc[a][b] = (floatx4){0.f, 0.f, 0.f, 0.f};

    for (int k0 = 0; k0 < H_DIM; k0 += BK) {
      #pragma unroll
      for (int i = 0; i < 4; ++i) {
        const unsigned short* ga = Xb + (size_t)m0 * H_DIM + rowOff[i] + k0;
        __builtin_amdgcn_global_load_lds(
            (const __attribute__((address_space(1))) void*)ga,
            (__attribute__((address_space(3))) void*)(&ldsA[ldsOff[i] * 8]),
            16, 0, 0);
        const unsigned short* gb = Wt + (size_t)n0 * H_DIM + rowOff[i] + k0;
        __builtin_amdgcn_global_load_lds(
            (const __attribute__((address_space(1))) void*)gb,
            (__attribute__((address_space(3))) void*)(&ldsB[ldsOff[i] * 8]),
            16, 0, 0);
      }
      __syncthreads();

      #pragma unroll
      for (int kk = 0; kk < BK; kk += 32) {
        const int c = (kk >> 3) + quad;
        bf16x8 af[4], bfr[4];
        #pragma unroll
        for (int rs = 0; rs < 4; ++rs) {
          int r = wy * 64 + rs * 16 + l16;
          af[rs] = *(const bf16x8*)&ldsA[(r * 8 + (c ^ (r & 7))) * 8];
        }
        #pragma unroll
        for (int ns = 0; ns < 4; ++ns) {
          int n = wx * 64 + ns * 16 + l16;
          bfr[ns] = *(const bf16x8*)&ldsB[(n * 8 + (c ^ (n & 7))) * 8];
        }
        #pragma unroll
        for (int rs = 0; rs < 4; ++rs)
          #pragma unroll
          for (int ns = 0; ns < 4; ++ns)
            acc[rs][ns] = __builtin_amdgcn_mfma_f32_16x16x32_bf16(
                af[rs], bfr[ns], acc[rs][ns], 0, 0, 0);
      }
      __syncthreads();
    }

    #pragma unroll
    for (int ns = 0; ns < 4; ++ns) {
      int n = n0 + wx * 64 + ns * 16 + l16;
      float p = proj[n];
      #pragma unroll
      for (int rs = 0; rs < 4; ++rs)
        #pragma unroll
        for (int gg = 0; gg < 4; ++gg)
          sc[rs][gg] += fast_tanh(acc[rs][ns][gg]) * p;
    }
  }

  #pragma unroll
  for (int rs = 0; rs < 4; ++rs)
    #pragma unroll
    for (int gg = 0; gg < 4; ++gg) {
      float v = sc[rs][gg];
      v += __shfl_xor(v, 1);
      v += __shfl_xor(v, 2);
      v += __shfl_xor(v, 4);
      v += __shfl_xor(v, 8);
      if (l16 == 0) {
        int row = m0 + wy * 64 + rs * 16 + quad * 4 + gg;
        atomicAdd(&scores[row], v);
      }
    }
}

// ---------------- windowed softmax + weighted sum (bf16 taps) ----------------
__global__ void out_kernel_bf16(const float* __restrict__ x,
                                const unsigned short* __restrict__ xb,
                                const float* __restrict__ scores,
                                const int* __restrict__ wp,
                                float* __restrict__ out) {
  int w = *wp;
  int t0 = blockIdx.x * TCHUNK;
  int b  = blockIdx.y;
  int h  = threadIdx.x;                 // 4-element group within row
  const float4* x4 = (const float4*)x;
  float4* o4 = (float4*)out;
  const ushort4* xb4 = (const ushort4*)xb;

  if (w == 3) {
    float4 z = {0.f, 0.f, 0.f, 0.f};
    float4 a0, a1, a2;
    float  s0, s1, s2;
    #pragma unroll
    for (int j = 0; j < 3; ++j) {
      int tm = t0 - 3 + j;
      float4 a = z; float s = 0.f;
      if (tm >= 0) {
        ushort4 u = xb4[((size_t)tm * B_DIM + b) * 256 + h];
        a.x = bf2f(u.x); a.y = bf2f(u.y); a.z = bf2f(u.z); a.w = bf2f(u.w);
        s = scores[tm * B_DIM + b];
      }
      if (j == 0) { a0 = a; s0 = s; }
      else if (j == 1) { a1 = a; s1 = s; }
      else { a2 = a; s2 = s; }
    }
    for (int i = 0; i < TCHUNK; ++i) {
      int t = t0 + i;
      size_t rbase = ((size_t)t * B_DIM + b) * 256 + h;
      ushort4 u = xb4[rbase];
      float4 v;
      v.x = bf2f(u.x); v.y = bf2f(u.y); v.z = bf2f(u.z); v.w = bf2f(u.w);
      float sv = scores[t * B_DIM + b];
      if (t < 3) {
        o4[rbase] = x4[rbase];           // exact fp32 passthrough
      } else {
        float m = fmaxf(fmaxf(s0, s1), s2);
        float e0 = __expf(s0 - m), e1 = __expf(s1 - m), e2 = __expf(s2 - m);
        float inv = 1.0f / (e0 + e1 + e2);
        e0 *= inv; e1 *= inv; e2 *= inv;
        float4 o;
        o.x = e0 * a0.x + e1 * a1.x + e2 * a2.x;
        o.y = e0 * a0.y + e1 * a1.y + e2 * a2.y;
        o.z = e0 * a0.z + e1 * a1.z + e2 * a2.z;
        o.w = e0 * a0.w + e1 * a1.w + e2 * a2.w;
        o4[rbase] = o;
      }
      a0 = a1; a1 = a2; a2 = v;
      s0 = s1; s1 = s2; s2 = sv;
    }
  } else {
    if (w > 8) w = 8;
    for (int i = 0; i < TCHUNK; ++i) {
      int t = t0 + i;
      size_t rbase = ((size_t)t * B_DIM + b) * 256 + h;
      if (t < w) { o4[rbase] = x4[rbase]; continue; }
      float s[8];
      float mx = -1e30f;
      for (int j = 0; j < w; ++j) {
        s[j] = scores[(t - w + j) * B_DIM + b];
        mx = fmaxf(mx, s[j]);
      }
      float sum = 0.f;
      for (int j = 0; j < w; ++j) { s[j] = __expf(s[j] - mx); sum += s[j]; }
      float inv = 1.0f / sum;
      float4 o = {0.f, 0.f, 0.f, 0.f};
      for (int j = 0; j < w; ++j) {
        float a = s[j] * inv;
        float4 v = x4[((size_t)(t - w + j) * B_DIM + b) * 256 + h];
        o.x += a * v.x; o.y += a * v.y; o.z += a * v.z; o.w += a * v.w;
      }
      o4[rbase] = o;
    }
  }
}

// ---------------- fp32-tap fallback (Xb aliases d_out; can't read it here) --
__global__ void out_kernel_f32(const float* __restrict__ x,
                               const float* __restrict__ scores,
                               const int* __restrict__ wp,
                               float* __restrict__ out) {
  int w = *wp;
  int t0 = blockIdx.x * TCHUNK;
  int b  = blockIdx.y;
  int h  = threadIdx.x;
  const float4* x4 = (const float4*)x;
  float4* o4 = (float4*)out;

  if (w == 3) {
    float4 z = {0.f, 0.f, 0.f, 0.f};
    float4 a0, a1, a2;
    float  s0, s1, s2;
    {
      int tm = t0 - 3;
      a0 = (tm >= 0) ? x4[((size_t)tm * B_DIM + b) * 256 + h] : z;
      s0 = (tm >= 0) ? scores[tm * B_DIM + b] : 0.f;
      tm = t0 - 2;
      a1 = (tm >= 0) ? x4[((size_t)tm * B_DIM + b) * 256 + h] : z;
      s1 = (tm >= 0) ? scores[tm * B_DIM + b] : 0.f;
      tm = t0 - 1;
      a2 = (tm >= 0) ? x4[((size_t)tm * B_DIM + b) * 256 + h] : z;
      s2 = (tm >= 0) ? scores[tm * B_DIM + b] : 0.f;
    }
    for (int i = 0; i < TCHUNK; ++i) {
      int t = t0 + i;
      size_t rbase = ((size_t)t * B_DIM + b) * 256 + h;
      float4 v = x4[rbase];
      float  sv = scores[t * B_DIM + b];
      if (t < 3) {
        o4[rbase] = v;
      } else {
        float m = fmaxf(fmaxf(s0, s1), s2);
        float e0 = __expf(s0 - m), e1 = __expf(s1 - m), e2 = __expf(s2 - m);
        float inv = 1.0f / (e0 + e1 + e2);
        e0 *= inv; e1 *= inv; e2 *= inv;
        float4 o;
        o.x = e0 * a0.x + e1 * a1.x + e2 * a2.x;
        o.y = e0 * a0.y + e1 * a1.y + e2 * a2.y;
        o.z = e0 * a0.z + e1 * a1.z + e2 * a2.z;
        o.w = e0 * a0.w + e1 * a1.w + e2 * a2.w;
        o4[rbase] = o;
      }
      a0 = a1; a1 = a2; a2 = v;
      s0 = s1; s1 = s2; s2 = sv;
    }
  } else {
    if (w > 8) w = 8;
    for (int i = 0; i < TCHUNK; ++i) {
      int t = t0 + i;
      size_t rbase = ((size_t)t * B_DIM + b) * 256 + h;
      if (t < w) { o4[rbase] = x4[rbase]; continue; }
      float s[8];
      float mx = -1e30f;
      for (int j = 0; j < w; ++j) {
        s[j] = scores[(t - w + j) * B_DIM + b];
        mx = fmaxf(mx, s[j]);
      }
      float sum = 0.f;
      for (int j = 0; j < w; ++j) { s[j] = __expf(s[j] - mx); sum += s[j]; }
      float inv = 1.0f / sum;
      float4 o = {0.f, 0.f, 0.f, 0.f};
      for (int j = 0; j < w; ++j) {
        float a = s[j] * inv;
        float4 v = x4[((size_t)(t - w + j) * B_DIM + b) * 256 + h];
        o.x += a * v.x; o.y += a * v.y; o.z += a * v.z; o.w += a * v.w;
      }
      o4[rbase] = o;
    }
  }
}

extern "C" void kernel_launch(void* const* d_in, const int* in_sizes, int n_in,
                              void* d_out, int out_size, void* d_ws, size_t ws_size,
                              hipStream_t stream) {
  const float* x    = (const float*)d_in[0];
  const float* w    = (const float*)d_in[1];
  const float* proj = (const float*)d_in[2];
  const int*   wp   = (const int*)d_in[3];
  float* out = (float*)d_out;

  const size_t XB_BYTES = (size_t)64 * 1024 * 1024;
  const size_t WT_BYTES = (size_t)2 * 1024 * 1024;
  const size_t need = XB_BYTES + WT_BYTES + (size_t)M_DIM * sizeof(float);
  const bool use_ws = ws_size >= need;

  unsigned short* Xb;
  unsigned short* Wt;
  float* scores;
  if (use_ws) {
    Xb = (unsigned short*)d_ws;
    Wt = (unsigned short*)((char*)d_ws + XB_BYTES);
    scores = (float*)((char*)d_ws + XB_BYTES + WT_BYTES);
  } else {
    Xb = (unsigned short*)d_out;
    Wt = (unsigned short*)((char*)d_out + XB_BYTES);
    scores = (float*)d_ws;
  }

  hipMemsetAsync(scores, 0, M_DIM * sizeof(float), stream);

  prep_kernel<<<CONV_BLOCKS + 1024, 256, 0, stream>>>(x, Xb, w, Wt);
  score_gemm_kernel<<<1024, 256, 0, stream>>>(Xb, Wt, proj, scores);
  if (use_ws)
    out_kernel_bf16<<<dim3(T_DIM / TCHUNK, B_DIM), 256, 0, stream>>>(x, Xb, scores, wp, out);
  else
    out_kernel_f32<<<dim3(T_DIM / TCHUNK, B_DIM), 256, 0, stream>>>(x, scores, wp, out);
}

// Round 4
// 349.842 us; speedup vs baseline: 1.0025x; 1.0025x over previous
//
#include <hip/hip_runtime.h>
#include <stdint.h>

#define T_DIM 2048
#define B_DIM 16
#define H_DIM 1024
#define M_DIM (T_DIM * B_DIM)   // 32768 rows
#define BK 64
#define TCHUNK 32

typedef __attribute__((ext_vector_type(8))) short bf16x8;
typedef __attribute__((ext_vector_type(4))) float floatx4;

__device__ inline unsigned short f2bf(float f) {
  union { float f; unsigned int u; } c; c.f = f;
  unsigned int u = c.u;
  return (unsigned short)((u + 0x7FFFu + ((u >> 16) & 1u)) >> 16);  // RNE
}

__device__ inline float fast_tanh(float x) {
  float e = __expf(2.0f * x);
  return 1.0f - 2.0f / (e + 1.0f);
}

// 8 f32 -> bf16x8 via v_cvt_pk_bf16_f32 (RNE, same rounding as f2bf).
// No builtin on gfx950 (m240) -> inline asm.
__device__ __forceinline__ bf16x8 cvt8(float4 lo, float4 hi) {
  union { bf16x8 v; unsigned int u[4]; } r;
  asm("v_cvt_pk_bf16_f32 %0, %1, %2" : "=v"(r.u[0]) : "v"(lo.x), "v"(lo.y));
  asm("v_cvt_pk_bf16_f32 %0, %1, %2" : "=v"(r.u[1]) : "v"(lo.z), "v"(lo.w));
  asm("v_cvt_pk_bf16_f32 %0, %1, %2" : "=v"(r.u[2]) : "v"(hi.x), "v"(hi.y));
  asm("v_cvt_pk_bf16_f32 %0, %1, %2" : "=v"(r.u[3]) : "v"(hi.z), "v"(hi.w));
  return r.v;
}

// ---------------- W[K][N] fp32 -> Wt[N][K] bf16 (2 MB, tiny) ----------------
__global__ void transpose_w_kernel(const float* __restrict__ w,
                                   unsigned short* __restrict__ wt) {
  __shared__ float tile[32][33];
  int tx = threadIdx.x, ty = threadIdx.y;
  int n0 = blockIdx.x * 32, k0 = blockIdx.y * 32;
  for (int i = ty; i < 32; i += 8)
    tile[i][tx] = w[(size_t)(k0 + i) * H_DIM + n0 + tx];
  __syncthreads();
  for (int i = ty; i < 32; i += 8)
    wt[(size_t)(n0 + i) * H_DIM + k0 + tx] = f2bf(tile[tx][i]);
}

// ---------------- scores = tanh(X@W)@proj, fp32 A direct ----------------
// PROVEN R0 schedule (79 us) with ONE change: A is staged as fp32 straight
// from x via global_load_lds (no separate convert kernel, no Xb buffer),
// converted to bf16 at fragment-read with v_cvt_pk_bf16_f32. Saves the
// 192 MB convert round-trip; gemm had 8x BW headroom (636 GB/s observed).
// A LDS tile [128][64] f32 = 32 KB, 16B-granule swizzle g^(row&15):
// fragment read (granules {2c,2c+1}^(row&15)) gives 16 distinct granules
// across l16 -> 2-way bank aliasing only (free, m136).
// Scores: 8 partials [(split*2+wx)][row] written non-atomically (single
// writer each), summed in out_kernel -> no memset dispatch, no atomics.
// XCD swizzle: 4 N-splits of one 128-row A-slab land on the same XCD.
__global__ __launch_bounds__(256, 3)
void score_gemm_kernel(const float* __restrict__ X,
                       const unsigned short* __restrict__ Wt,
                       const float* __restrict__ proj,
                       float* __restrict__ scoresP) {
  __shared__ __align__(16) float ldsAf[128 * 64];          // 32 KiB
  __shared__ __align__(16) unsigned short ldsB[128 * 64];  // 16 KiB

  const int tid  = threadIdx.x;
  const int lane = tid & 63;
  const int wave = tid >> 6;
  const int wy = wave >> 1, wx = wave & 1;
  const int quad = lane >> 4, l16 = lane & 15;

  const int idx   = blockIdx.x;
  const int x7    = idx & 7;
  const int split = (idx >> 3) & 3;
  const int g     = idx >> 5;
  const int bm    = g * 8 + x7;        // 0..255
  const int m0    = bm * 128;
  const int nbase = split * 256;

  // A staging (fp32): 8 issues x 4KB. Linear LDS granule s = i*256+tid;
  // row = s>>4, pos = s&15; global source granule = pos ^ (row&15).
  int gOffA[8], ldsAOff[8];
  #pragma unroll
  for (int i = 0; i < 8; ++i) {
    int s = i * 256 + wave * 64 + lane;
    int row = s >> 4, gg = s & 15;
    int sg = gg ^ (row & 15);
    gOffA[i] = row * H_DIM + sg * 4;            // f32 elements
    ldsAOff[i] = (i * 256 + wave * 64) * 4;     // f32 index of wave base
  }
  // B staging (bf16): 4 issues, 8-elem granules, swizzle cs^(row&7).
  int gOffB[4], ldsBOff[4];
  #pragma unroll
  for (int i = 0; i < 4; ++i) {
    int cb = (i * 4 + wave) * 64;
    int s = cb + lane;
    int row = s >> 3, cs = s & 7;
    int cg = cs ^ (row & 7);
    gOffB[i] = row * H_DIM + cg * 8;
    ldsBOff[i] = cb * 8;
  }

  float sc[4][4];
  #pragma unroll
  for (int a = 0; a < 4; ++a)
    #pragma unroll
    for (int b = 0; b < 4; ++b) sc[a][b] = 0.0f;

  for (int n0 = nbase; n0 < nbase + 256; n0 += 128) {
    floatx4 acc[4][4];
    #pragma unroll
    for (int a = 0; a < 4; ++a)
      #pragma unroll
      for (int b = 0; b < 4; ++b) acc[a][b] = (floatx4){0.f, 0.f, 0.f, 0.f};

    for (int k0 = 0; k0 < H_DIM; k0 += BK) {
      #pragma unroll
      for (int i = 0; i < 8; ++i) {
        const float* ga = X + (size_t)m0 * H_DIM + gOffA[i] + k0;
        __builtin_amdgcn_global_load_lds(
            (const __attribute__((address_space(1))) void*)ga,
            (__attribute__((address_space(3))) void*)(&ldsAf[ldsAOff[i]]),
            16, 0, 0);
      }
      #pragma unroll
      for (int i = 0; i < 4; ++i) {
        const unsigned short* gb = Wt + (size_t)n0 * H_DIM + gOffB[i] + k0;
        __builtin_amdgcn_global_load_lds(
            (const __attribute__((address_space(1))) void*)gb,
            (__attribute__((address_space(3))) void*)(&ldsB[ldsBOff[i]]),
            16, 0, 0);
      }
      __syncthreads();

      #pragma unroll
      for (int kk = 0; kk < BK; kk += 32) {
        const int c = (kk >> 3) + quad;          // 32B-pair index 0..7
        bf16x8 af[4], bfr[4];
        #pragma unroll
        for (int rs = 0; rs < 4; ++rs) {
          int r = wy * 64 + rs * 16 + l16;
          const float4 lo =
              *(const float4*)&ldsAf[r * 64 + (((2 * c)     ^ (r & 15)) << 2)];
          const float4 hi =
              *(const float4*)&ldsAf[r * 64 + (((2 * c + 1) ^ (r & 15)) << 2)];
          af[rs] = cvt8(lo, hi);
        }
        #pragma unroll
        for (int ns = 0; ns < 4; ++ns) {
          int n = wx * 64 + ns * 16 + l16;
          bfr[ns] = *(const bf16x8*)&ldsB[(n * 8 + (c ^ (n & 7))) * 8];
        }
        #pragma unroll
        for (int rs = 0; rs < 4; ++rs)
          #pragma unroll
          for (int ns = 0; ns < 4; ++ns)
            acc[rs][ns] = __builtin_amdgcn_mfma_f32_16x16x32_bf16(
                af[rs], bfr[ns], acc[rs][ns], 0, 0, 0);
      }
      __syncthreads();
    }

    #pragma unroll
    for (int ns = 0; ns < 4; ++ns) {
      int n = n0 + wx * 64 + ns * 16 + l16;
      float p = proj[n];
      #pragma unroll
      for (int rs = 0; rs < 4; ++rs)
        #pragma unroll
        for (int gg = 0; gg < 4; ++gg)
          sc[rs][gg] += fast_tanh(acc[rs][ns][gg]) * p;
    }
  }

  // one writer per (split, wx, row) -> plain store, no memset needed
  #pragma unroll
  for (int rs = 0; rs < 4; ++rs)
    #pragma unroll
    for (int gg = 0; gg < 4; ++gg) {
      float v = sc[rs][gg];
      v += __shfl_xor(v, 1);
      v += __shfl_xor(v, 2);
      v += __shfl_xor(v, 4);
      v += __shfl_xor(v, 8);
      if (l16 == 0) {
        int row = m0 + wy * 64 + rs * 16 + quad * 4 + gg;
        scoresP[(size_t)(split * 2 + wx) * M_DIM + row] = v;
      }
    }
}

// ---------------- windowed softmax + weighted sum (fp32 taps) ---------------
__global__ void out_kernel(const float* __restrict__ x,
                           const float* __restrict__ sp,
                           const int* __restrict__ wp,
                           float* __restrict__ out) {
  int w = *wp;
  int t0 = blockIdx.x * TCHUNK;
  int b  = blockIdx.y;
  int h  = threadIdx.x;
  const float4* x4 = (const float4*)x;
  float4* o4 = (float4*)out;

  auto SC = [&](int i) {
    float s = 0.f;
    #pragma unroll
    for (int p = 0; p < 8; ++p) s += sp[(size_t)p * M_DIM + i];
    return s;
  };

  if (w == 3) {
    float4 z = {0.f, 0.f, 0.f, 0.f};
    float4 a0, a1, a2;
    float  s0, s1, s2;
    {
      int tm = t0 - 3;
      a0 = (tm >= 0) ? x4[((size_t)tm * B_DIM + b) * 256 + h] : z;
      s0 = (tm >= 0) ? SC(tm * B_DIM + b) : 0.f;
      tm = t0 - 2;
      a1 = (tm >= 0) ? x4[((size_t)tm * B_DIM + b) * 256 + h] : z;
      s1 = (tm >= 0) ? SC(tm * B_DIM + b) : 0.f;
      tm = t0 - 1;
      a2 = (tm >= 0) ? x4[((size_t)tm * B_DIM + b) * 256 + h] : z;
      s2 = (tm >= 0) ? SC(tm * B_DIM + b) : 0.f;
    }
    for (int i = 0; i < TCHUNK; ++i) {
      int t = t0 + i;
      size_t rbase = ((size_t)t * B_DIM + b) * 256 + h;
      float4 v = x4[rbase];
      float  sv = SC(t * B_DIM + b);
      if (t < 3) {
        o4[rbase] = v;                       // exact fp32 passthrough
      } else {
        float m = fmaxf(fmaxf(s0, s1), s2);
        float e0 = __expf(s0 - m), e1 = __expf(s1 - m), e2 = __expf(s2 - m);
        float inv = 1.0f / (e0 + e1 + e2);
        e0 *= inv; e1 *= inv; e2 *= inv;
        float4 o;
        o.x = e0 * a0.x + e1 * a1.x + e2 * a2.x;
        o.y = e0 * a0.y + e1 * a1.y + e2 * a2.y;
        o.z = e0 * a0.z + e1 * a1.z + e2 * a2.z;
        o.w = e0 * a0.w + e1 * a1.w + e2 * a2.w;
        o4[rbase] = o;
      }
      a0 = a1; a1 = a2; a2 = v;
      s0 = s1; s1 = s2; s2 = sv;
    }
  } else {
    if (w > 8) w = 8;
    for (int i = 0; i < TCHUNK; ++i) {
      int t = t0 + i;
      size_t rbase = ((size_t)t * B_DIM + b) * 256 + h;
      if (t < w) { o4[rbase] = x4[rbase]; continue; }
      float s[8];
      float mx = -1e30f;
      for (int j = 0; j < w; ++j) {
        s[j] = SC((t - w + j) * B_DIM + b);
        mx = fmaxf(mx, s[j]);
      }
      float sum = 0.f;
      for (int j = 0; j < w; ++j) { s[j] = __expf(s[j] - mx); sum += s[j]; }
      float inv = 1.0f / sum;
      float4 o = {0.f, 0.f, 0.f, 0.f};
      for (int j = 0; j < w; ++j) {
        float a = s[j] * inv;
        float4 v = x4[((size_t)(t - w + j) * B_DIM + b) * 256 + h];
        o.x += a * v.x; o.y += a * v.y; o.z += a * v.z; o.w += a * v.w;
      }
      o4[rbase] = o;
    }
  }
}

extern "C" void kernel_launch(void* const* d_in, const int* in_sizes, int n_in,
                              void* d_out, int out_size, void* d_ws, size_t ws_size,
                              hipStream_t stream) {
  const float* x    = (const float*)d_in[0];
  const float* w    = (const float*)d_in[1];
  const float* proj = (const float*)d_in[2];
  const int*   wp   = (const int*)d_in[3];
  float* out = (float*)d_out;

  const size_t WT_BYTES = (size_t)2 * 1024 * 1024;
  const size_t SP_BYTES = (size_t)8 * M_DIM * sizeof(float);   // 1 MiB
  const bool use_ws = ws_size >= WT_BYTES + SP_BYTES;

  unsigned short* Wt;
  float* scoresP;
  if (use_ws) {
    Wt = (unsigned short*)d_ws;
    scoresP = (float*)((char*)d_ws + WT_BYTES);
  } else {
    // Wt in d_out head is safe: only gemm reads it, and gemm completes
    // before out_kernel's first write (stream order). scoresP must survive
    // out_kernel -> keep in d_ws (needs 1 MiB).
    Wt = (unsigned short*)d_out;
    scoresP = (float*)d_ws;
  }

  transpose_w_kernel<<<dim3(32, 32), dim3(32, 8), 0, stream>>>(w, Wt);
  score_gemm_kernel<<<1024, 256, 0, stream>>>(x, Wt, proj, scoresP);
  out_kernel<<<dim3(T_DIM / TCHUNK, B_DIM), 256, 0, stream>>>(x, scoresP, wp, out);
}